// Round 2
// baseline (575.822 us; speedup 1.0000x reference)
//
#include <hip/hip_runtime.h>
#include <math.h>

#define Dk 1024
#define Ck 32
#define Nk 1024
#define Qk 1024
#define REGP 0.5f
#define NB 64
#define NROWSV (Qk + Nk + Ck + 1)   // 2081 rows: queries, sorted support, mus, m

// consts layout (floats)
#define CO_KAPPA 0
#define CO_NU    1
#define CO_NJ    2
#define CO_KN    34
#define CO_SCALE 66
#define CO_COMMON 98
#define CO_COEF  130
#define CO_BIASA 162
#define CO_BIASF 200

// workspace offsets (floats). P aliases Y (Y dead after k_cvt, P born in k_p4m).
#define O_Y    0u
#define O_P    0u
#define O_W    2162688u
#define O_T    3211264u
#define O_MU   3473408u
#define O_QM   3506176u
#define O_MB   3538944u
#define O_MI   3578112u
#define O_QNY  3617280u
#define O_QNO  3618304u
#define O_MUN  3619328u
#define O_GMM  3619360u
#define O_EX   3619392u
#define O_CONS 3619408u
#define O_CIDX 3619664u
// bf16 split matrices (ushort storage, offsets in floats)
#define O_YH   3652432u
#define O_YM   4733776u
#define O_YL   5815120u
#define O_WH   6896464u
#define O_WM   7420752u
#define O_WL   7945040u
#define O_OH   8469328u
#define O_OM   9550672u
#define O_OL   10632016u
// total = 11,713,360 floats = 46.9 MB

#define WS_DECL \
    float* Y     = Wbuf + O_Y;    (void)Y; \
    float* P     = Wbuf + O_P;    (void)P; \
    float* W     = Wbuf + O_W;    (void)W; \
    float* Tb    = Wbuf + O_T;    (void)Tb; \
    float* mu    = Wbuf + O_MU;   (void)mu; \
    float* QM    = Wbuf + O_QM;   (void)QM; \
    float* Mbuf  = Wbuf + O_MB;   (void)Mbuf; \
    float* Minv  = Wbuf + O_MI;   (void)Minv; \
    float* qny   = Wbuf + O_QNY;  (void)qny; \
    float* qno   = Wbuf + O_QNO;  (void)qno; \
    float* mun2o = Wbuf + O_MUN;  (void)mun2o; \
    float* gmm   = Wbuf + O_GMM;  (void)gmm; \
    float* extraf= Wbuf + O_EX;   (void)extraf; \
    float* cons  = Wbuf + O_CONS; (void)cons; \
    int*   cidx  = (int*)(Wbuf + O_CIDX); (void)cidx; \
    ushort* sYh = (ushort*)(Wbuf + O_YH); (void)sYh; \
    ushort* sYm = (ushort*)(Wbuf + O_YM); (void)sYm; \
    ushort* sYl = (ushort*)(Wbuf + O_YL); (void)sYl; \
    ushort* sWh = (ushort*)(Wbuf + O_WH); (void)sWh; \
    ushort* sWm = (ushort*)(Wbuf + O_WM); (void)sWm; \
    ushort* sWl = (ushort*)(Wbuf + O_WL); (void)sWl; \
    ushort* sOh = (ushort*)(Wbuf + O_OH); (void)sOh; \
    ushort* sOm = (ushort*)(Wbuf + O_OM); (void)sOm; \
    ushort* sOl = (ushort*)(Wbuf + O_OL); (void)sOl;

typedef __attribute__((ext_vector_type(8))) __bf16 bf16x8;
typedef __attribute__((ext_vector_type(4))) float f32x4;

#define MFMA(a, b, c) __builtin_amdgcn_mfma_f32_16x16x32_bf16(a, b, c, 0, 0, 0)

__device__ __forceinline__ ushort f2bf(float x) {
    unsigned u = __float_as_uint(x);
    return (ushort)((u + 0x7FFFu + ((u >> 16) & 1u)) >> 16);
}
__device__ __forceinline__ float bf2f(ushort h) {
    return __uint_as_float(((unsigned)h) << 16);
}
__device__ __forceinline__ bf16x8 ld8(const ushort* p) {
    return *(const bf16x8*)p;
}

__device__ __forceinline__ float wave_red(float s) {
#pragma unroll
    for (int o = 32; o > 0; o >>= 1) s += __shfl_down(s, o, 64);
    return s;
}

// ---------- fp32 tile-GEMM machinery (still used by trtri chain) ----------
__device__ __forceinline__ void fetch4(float4* reg, const float* src, int ld,
                                       int rowbase, int rowmax, int colbase, int t) {
#pragma unroll
    for (int u = 0; u < 4; ++u) {
        int slot = t + u * 256;
        int r = slot >> 4, c4 = slot & 15;
        int gr = rowbase + r;
        reg[u] = (gr < rowmax) ? *(const float4*)(src + (size_t)gr * ld + colbase + c4 * 4)
                               : make_float4(0.f, 0.f, 0.f, 0.f);
    }
}
__device__ __forceinline__ void stT(float* dst, const float4* reg, int t) {
#pragma unroll
    for (int u = 0; u < 4; ++u) {
        int slot = t + u * 256;
        int r = slot >> 4, c4 = slot & 15;
        dst[(c4 * 4 + 0) * 68 + r] = reg[u].x;
        dst[(c4 * 4 + 1) * 68 + r] = reg[u].y;
        dst[(c4 * 4 + 2) * 68 + r] = reg[u].z;
        dst[(c4 * 4 + 3) * 68 + r] = reg[u].w;
    }
}
__device__ __forceinline__ void stN(float* dst, const float4* reg, int t) {
#pragma unroll
    for (int u = 0; u < 4; ++u) {
        int slot = t + u * 256;
        int r = slot >> 4, c4 = slot & 15;
        *(float4*)(dst + r * 68 + c4 * 4) = reg[u];
    }
}
__device__ __forceinline__ void gemm16(const float* At, const float* Bt,
                                       float acc[4][4], int tx, int ty) {
#pragma unroll 4
    for (int kk = 0; kk < NB; ++kk) {
        float4 a = *(const float4*)(At + kk * 68 + ty * 4);
        float4 b = *(const float4*)(Bt + kk * 68 + tx * 4);
        float av[4] = {a.x, a.y, a.z, a.w};
        float bv[4] = {b.x, b.y, b.z, b.w};
#pragma unroll
        for (int r = 0; r < 4; ++r)
#pragma unroll
            for (int s = 0; s < 4; ++s) acc[r][s] += av[r] * bv[s];
    }
}
__device__ __forceinline__ void mm_task(
    const float* aSrc, int aLd, int aRow, int aRowMax, int aCol, int aRowStep, int aColStep,
    const float* bSrc, int bLd, int bRow, int bRowMax, int bCol, int bRowStep, int bColStep,
    bool bTrans, int k0, int k1,
    float acc[4][4], float* smA, float* smB, int t, int tx, int ty)
{
    float4 ra[4], rb[4];
    fetch4(ra, aSrc, aLd, aRow + k0 * aRowStep, aRowMax, aCol + k0 * aColStep, t);
    fetch4(rb, bSrc, bLd, bRow + k0 * bRowStep, bRowMax, bCol + k0 * bColStep, t);
    stT(smA, ra, t);
    if (bTrans) stT(smB, rb, t); else stN(smB, rb, t);
    __syncthreads();
    for (int kt = k0; kt < k1; ++kt) {
        if (kt + 1 < k1) {
            fetch4(ra, aSrc, aLd, aRow + (kt + 1) * aRowStep, aRowMax, aCol + (kt + 1) * aColStep, t);
            fetch4(rb, bSrc, bLd, bRow + (kt + 1) * bRowStep, bRowMax, bCol + (kt + 1) * bColStep, t);
        }
        gemm16(smA, smB, acc, tx, ty);
        __syncthreads();
        if (kt + 1 < k1) {
            stT(smA, ra, t);
            if (bTrans) stT(smB, rb, t); else stN(smB, rb, t);
        }
        __syncthreads();
    }
}

// ========== P0: stats, logdet, diag trtri, zero accum bufs, qno, copies (grid 152) ==========
__global__ __launch_bounds__(256) void k_p0(const float* qx, const int* labels,
                                            const float* mvec, const float* kappa,
                                            const float* nu, const float* td,
                                            const float* tl, float* Wbuf) {
    __shared__ __align__(16) float smem[9216];
    float* smA = smem;
    float* smB = smem + 4352;
    float* sX  = smem + 8704;
    WS_DECL
    const int t = threadIdx.x;
    const int lane = t & 63, wv = t >> 6;
    const int tau = blockIdx.x;

    if (tau == 0) {
        int* scnt = (int*)sX;
        if (t < Ck) scnt[t] = 0;
        __syncthreads();
        for (int n = t; n < Nk; n += 256) {
            int l = labels[n];
            int pos = atomicAdd(&scnt[l], 1);
            cidx[l * Nk + pos] = n;
        }
        __syncthreads();
        if (t < Ck) {
            float kap = fabsf(kappa[0]) + 1e-6f;
            float nu_ = fmaxf(nu[0], (float)(Dk - 1) + 1e-6f);
            float Njf = (float)scnt[t];
            float kN = kap + Njf;
            if (t == 0) { cons[CO_KAPPA] = kap; cons[CO_NU] = nu_; }
            cons[CO_NJ + t] = Njf;
            cons[CO_KN + t] = kN;
            cons[CO_SCALE + t] = (kN + 1.0f) / ((nu_ + Njf - (float)Dk + 1.0f) * kN);
            float common = nu_ + Njf + 1.0f - (float)Dk;
            cons[CO_COMMON + t] = common;
            cons[CO_COEF + t] = 0.5f * (common + (float)Dk);
            cons[CO_BIASA + t] = lgammaf(0.5f * (common + (float)Dk)) - lgammaf(0.5f * common)
                                 - 0.5f * (float)Dk * logf(common);
        }
    } else if (tau == 1) {
        float s = 0.f;
        for (int i = t; i < Dk; i += 256) s += logf(fabsf(td[i]));
        s = wave_red(s);
        if (lane == 0) sX[wv] = s;
        __syncthreads();
        if (t == 0) extraf[0] = 2.f * (sX[0] + sX[1] + sX[2] + sX[3]);
    } else if (tau < 18) {
        int I = tau - 2, b0 = I * NB;
        for (int idx = t; idx < NB * NB; idx += 256) {
            int r = idx >> 6, c = idx & 63;
            float v;
            if (c < r) v = tl[(size_t)(b0 + r) * Dk + b0 + c];
            else if (c == r) v = fabsf(td[b0 + r]);
            else v = 0.f;
            smA[r * 68 + c] = v;
        }
        __syncthreads();
        if (t < NB) {
            int j = t;
            smB[j * 68 + j] = 1.f / smA[j * 68 + j];
            for (int i = j + 1; i < NB; ++i) {
                float s = 0.f;
                for (int k = j; k < i; ++k) s += smA[i * 68 + k] * smB[k * 68 + j];
                smB[i * 68 + j] = -s / smA[i * 68 + i];
            }
        }
        __syncthreads();
        for (int idx = t; idx < NB * NB; idx += 256) {
            int r = idx >> 6, c = idx & 63;
            W[(size_t)(b0 + r) * Dk + b0 + c] = (c <= r) ? smB[r * 68 + c] : 0.f;
        }
    } else if (tau < 21) {         // zero Mbuf (32*1224 = 39168)
        int base = (tau - 18) * 13056;
        for (int i = t; i < 13056 && base + i < 39168; i += 256) Mbuf[base + i] = 0.f;
    } else if (tau == 21) {        // zero mun2o, gmm
        if (t < 32) { mun2o[t] = 0.f; gmm[t] = 0.f; }
    } else if (tau < 86) {         // qno (16 rows/task)
        int rbase = (tau - 22) * 16;
        for (int j = wv; j < 16; j += 4) {
            const float* row = qx + (size_t)(rbase + j) * Dk;
            float s = 0.f;
            for (int d = lane; d < Dk; d += 64) { float v = row[d]; s += v * v; }
            s = wave_red(s);
            if (lane == 0) qno[rbase + j] = s;
        }
    } else if (tau < 150) {        // copy queries into Y
        int rbase = (tau - 86) * 16;
        for (int j = 0; j < 16; ++j) {
            int r = rbase + j;
            ((float4*)(Y + (size_t)r * Dk))[t] = ((const float4*)(qx + (size_t)r * Dk))[t];
        }
    } else if (tau == 150) {       // m row
        ((float4*)(Y + (size_t)(Qk + Nk + Ck) * Dk))[t] = ((const float4*)mvec)[t];
    } else {                       // zero Y tail rows 2081..2111
        float4* z = (float4*)(Y + (size_t)2081 * Dk);
        for (int i = t; i < 31 * 256; i += 256) z[i] = make_float4(0, 0, 0, 0);
    }
}

// ========== P1: mu (+Y mu-row +mun2o), sorted-support copy (grid 192) ==========
__global__ __launch_bounds__(256) void k_p1(const float* sx, const float* mvec, float* Wbuf) {
    __shared__ float sX[512];
    WS_DECL
    const int t = threadIdx.x;
    const int lane = t & 63, wv = t >> 6;
    const int tau = blockIdx.x;
    if (tau < 128) {
        int c = tau >> 2;
        int d = ((tau & 3) << 8) + t;
        int Nj = (int)cons[CO_NJ + c];
        float kap = cons[CO_KAPPA], kN = cons[CO_KN + c];
        float acc = 0.f;
        for (int s = 0; s < Nj; ++s) acc += sx[(size_t)cidx[c * Nk + s] * Dk + d];
        float muv = (kap * mvec[d] + acc) / kN;
        mu[c * Dk + d] = muv;
        Y[(size_t)(Qk + Nk + c) * Dk + d] = muv;
        float s2 = wave_red(muv * muv);
        if (lane == 0) sX[wv] = s2;
        __syncthreads();
        if (t == 0) atomicAdd(&mun2o[c], sX[0] + sX[1] + sX[2] + sX[3]);
    } else {
        int rbase = (tau - 128) * 16;
        for (int j = 0; j < 16; ++j) {
            int n = rbase + j;
            int srcrow = cidx[(n >> 5) * Nk + (n & 31)];
            ((float4*)(Y + (size_t)(Qk + n) * Dk))[t] = ((const float4*)(sx + (size_t)srcrow * Dk))[t];
        }
    }
}

// ========== T1: trtri level-1 (merged A+B, local) (grid 8) ==========
__global__ __launch_bounds__(256) void k_t1(const float* tl, float* Wbuf) {
    __shared__ __align__(16) float smem[8704];
    float* smA = smem;
    float* smB = smem + 4352;
    WS_DECL
    const int t = threadIdx.x;
    const int tx = t & 15, ty = t >> 4;
    const int BIG = 1 << 30;
    int pb = blockIdx.x * 128;
    float acc[4][4] = {};
    mm_task(tl, Dk, pb + 64, BIG, pb, 0, NB,
            W, Dk, pb, BIG, pb, NB, 0, false, 0, 1,
            acc, smA, smB, t, tx, ty);
    {
        float4 ra[4];
        fetch4(ra, W, Dk, pb + 64, BIG, pb + 64, t);
#pragma unroll
        for (int r = 0; r < 4; ++r)
#pragma unroll
            for (int s = 0; s < 4; ++s)
                smB[(ty * 4 + r) * 68 + tx * 4 + s] = acc[r][s];
        stT(smA, ra, t);
    }
    __syncthreads();
    float acc2[4][4] = {};
    gemm16(smA, smB, acc2, tx, ty);
    __syncthreads();
#pragma unroll
    for (int r = 0; r < 4; ++r)
#pragma unroll
        for (int s = 0; s < 4; ++s)
            W[(size_t)(pb + 64 + ty * 4 + r) * Dk + pb + tx * 4 + s] = -acc2[r][s];
}

// ========== trtri level l phase A: T = B * Ainv ==========
__global__ __launch_bounds__(256) void k_tr_a(const float* tl, float* Wbuf, int h, int ht) {
    __shared__ __align__(16) float smem[8704];
    float* smA = smem;
    float* smB = smem + 4352;
    WS_DECL
    const int t = threadIdx.x;
    const int tx = t & 15, ty = t >> 4;
    const int BIG = 1 << 30;
    int tau = blockIdx.x;
    int p = tau / (ht * ht), rr = tau % (ht * ht);
    int i = rr / ht, j = rr % ht;
    int pb = p * 2 * h;
    float acc[4][4] = {};
    mm_task(tl, Dk, pb + h + i * NB, BIG, pb, 0, NB,
            W, Dk, pb, BIG, pb + j * NB, NB, 0, false, 0, ht,
            acc, smA, smB, t, tx, ty);
    float* Tp = Tb + (size_t)p * h * h;
#pragma unroll
    for (int r = 0; r < 4; ++r)
#pragma unroll
        for (int s = 0; s < 4; ++s)
            Tp[(size_t)(i * NB + ty * 4 + r) * h + j * NB + tx * 4 + s] = acc[r][s];
}

// ========== trtri level l phase B: W_off = -Cinv * T ==========
__global__ __launch_bounds__(256) void k_tr_b(float* Wbuf, int h, int ht) {
    __shared__ __align__(16) float smem[8704];
    float* smA = smem;
    float* smB = smem + 4352;
    WS_DECL
    const int t = threadIdx.x;
    const int tx = t & 15, ty = t >> 4;
    const int BIG = 1 << 30;
    int tau = blockIdx.x;
    int p = tau / (ht * ht), rr = tau % (ht * ht);
    int i = rr / ht, j = rr % ht;
    int pb = p * 2 * h;
    const float* Tp = Tb + (size_t)p * h * h;
    float acc[4][4] = {};
    mm_task(W, Dk, pb + h + i * NB, BIG, pb + h, 0, NB,
            Tp, h, 0, BIG, j * NB, NB, 0, false, 0, ht,
            acc, smA, smB, t, tx, ty);
#pragma unroll
    for (int r = 0; r < 4; ++r)
#pragma unroll
        for (int s = 0; s < 4; ++s)
            W[(size_t)(pb + h + i * NB + ty * 4 + r) * Dk + pb + j * NB + tx * 4 + s] = -acc[r][s];
}

// ========== CVT: exact 3-way bf16 split of Y (2112x1024) and W (1024x1024) (grid 784) ==========
__global__ __launch_bounds__(256) void k_cvt(float* Wbuf) {
    WS_DECL
    const int t = threadIdx.x;
#pragma unroll
    for (int u = 0; u < 4; ++u) {
        unsigned g = blockIdx.x * 1024u + u * 256u + t;   // float4 index, 0..802815
        bool isY = g < 540672u;
        float4 v = isY ? ((const float4*)Y)[g] : ((const float4*)W)[g - 540672u];
        ushort* ph = isY ? sYh : sWh;
        ushort* pm = isY ? sYm : sWm;
        ushort* pl = isY ? sYl : sWl;
        size_t o = (size_t)(isY ? g : (g - 540672u)) * 4;
        float vv[4] = {v.x, v.y, v.z, v.w};
        ushort4 H, M, L;
        ushort* Hp = (ushort*)&H; ushort* Mp = (ushort*)&M; ushort* Lp = (ushort*)&L;
#pragma unroll
        for (int c = 0; c < 4; ++c) {
            float x = vv[c];
            ushort h = f2bf(x);
            float r1 = x - bf2f(h);
            ushort m_ = f2bf(r1);
            ushort lo = f2bf(r1 - bf2f(m_));
            Hp[c] = h; Mp[c] = m_; Lp[c] = lo;
        }
        *(ushort4*)(ph + o) = H;
        *(ushort4*)(pm + o) = M;
        *(ushort4*)(pl + o) = L;
    }
}

// ========== YG: Yo = Y * W^T via bf16x3 MFMA; writes Yo as bf16 splits (grid 1056) ==========
__global__ __launch_bounds__(256) void k_yg(float* Wbuf) {
    WS_DECL
    int e = blockIdx.x;
    int jt = 15 - (e & 15);           // col tile, descending for load balance
    int rt = e >> 4;                  // row tile (32 rows), 0..65
    int w = threadIdx.x >> 6, l = threadIdx.x & 63;
    int lr = l & 15, lk = l >> 4;
    size_t arow = (size_t)(rt * 32 + lr) * 1024 + lk * 8;
    size_t brow = (size_t)(jt * 64 + w * 16 + lr) * 1024 + lk * 8;
    f32x4 acc0 = {0.f, 0.f, 0.f, 0.f}, acc1 = {0.f, 0.f, 0.f, 0.f};
    int ksteps = (jt + 1) * 2;        // triangular: k < (jt+1)*64
    for (int ks = 0; ks < ksteps; ++ks) {
        size_t ko = (size_t)ks * 32;
        bf16x8 bh = ld8(sWh + brow + ko);
        bf16x8 bm = ld8(sWm + brow + ko);
        bf16x8 bl = ld8(sWl + brow + ko);
        bf16x8 a0h = ld8(sYh + arow + ko);
        bf16x8 a0m = ld8(sYm + arow + ko);
        bf16x8 a0l = ld8(sYl + arow + ko);
        bf16x8 a1h = ld8(sYh + arow + 16384 + ko);
        bf16x8 a1m = ld8(sYm + arow + 16384 + ko);
        bf16x8 a1l = ld8(sYl + arow + 16384 + ko);
        acc0 = MFMA(a0h, bh, acc0); acc1 = MFMA(a1h, bh, acc1);
        acc0 = MFMA(a0h, bm, acc0); acc1 = MFMA(a1h, bm, acc1);
        acc0 = MFMA(a0m, bh, acc0); acc1 = MFMA(a1m, bh, acc1);
        acc0 = MFMA(a0h, bl, acc0); acc1 = MFMA(a1h, bl, acc1);
        acc0 = MFMA(a0l, bh, acc0); acc1 = MFMA(a1l, bh, acc1);
        acc0 = MFMA(a0m, bm, acc0); acc1 = MFMA(a1m, bm, acc1);
    }
#pragma unroll
    for (int rtile = 0; rtile < 2; ++rtile) {
        f32x4 a = rtile ? acc1 : acc0;
#pragma unroll
        for (int r = 0; r < 4; ++r) {
            int grow = rt * 32 + rtile * 16 + lk * 4 + r;
            if (grow < NROWSV) {
                float v = a[r];
                size_t o = (size_t)grow * 1024 + jt * 64 + w * 16 + lr;
                ushort h = f2bf(v);
                float r1 = v - bf2f(h);
                ushort m_ = f2bf(r1);
                ushort lo = f2bf(r1 - bf2f(m_));
                sOh[o] = h; sOm[o] = m_; sOl[o] = lo;
            }
        }
    }
}

// ========== P4M: P = Yo_s * Yo_q^T (544 blocks) and QM = mu * qx^T (16 blocks) via MFMA ==========
__global__ __launch_bounds__(256) void k_p4m(float* Wbuf) {
    WS_DECL
    int e = blockIdx.x;
    int w = threadIdx.x >> 6, l = threadIdx.x & 63;
    int lr = l & 15, lk = l >> 4;
    bool isP = e < 544;
    int qt = isP ? (e & 15) : (e - 544);
    int rowbase = isP ? (1024 + (e >> 4) * 32) : 2048;
    const ushort* Ah = isP ? sOh : sYh;
    const ushort* Am = isP ? sOm : sYm;
    const ushort* Al = isP ? sOl : sYl;
    const ushort* Bh = isP ? sOh : sYh;
    const ushort* Bm = isP ? sOm : sYm;
    const ushort* Bl = isP ? sOl : sYl;
    size_t arow = (size_t)(rowbase + lr) * 1024 + lk * 8;
    size_t brow = (size_t)(qt * 64 + w * 16 + lr) * 1024 + lk * 8;
    f32x4 acc0 = {0.f, 0.f, 0.f, 0.f}, acc1 = {0.f, 0.f, 0.f, 0.f};
    for (int ks = 0; ks < 32; ++ks) {
        size_t ko = (size_t)ks * 32;
        bf16x8 bh = ld8(Bh + brow + ko);
        bf16x8 bm = ld8(Bm + brow + ko);
        bf16x8 bl = ld8(Bl + brow + ko);
        bf16x8 a0h = ld8(Ah + arow + ko);
        bf16x8 a0m = ld8(Am + arow + ko);
        bf16x8 a0l = ld8(Al + arow + ko);
        bf16x8 a1h = ld8(Ah + arow + 16384 + ko);
        bf16x8 a1m = ld8(Am + arow + 16384 + ko);
        bf16x8 a1l = ld8(Al + arow + 16384 + ko);
        acc0 = MFMA(a0h, bh, acc0); acc1 = MFMA(a1h, bh, acc1);
        acc0 = MFMA(a0h, bm, acc0); acc1 = MFMA(a1h, bm, acc1);
        acc0 = MFMA(a0m, bh, acc0); acc1 = MFMA(a1m, bh, acc1);
        acc0 = MFMA(a0h, bl, acc0); acc1 = MFMA(a1h, bl, acc1);
        acc0 = MFMA(a0l, bh, acc0); acc1 = MFMA(a1l, bh, acc1);
        acc0 = MFMA(a0m, bm, acc0); acc1 = MFMA(a1m, bm, acc1);
    }
    int q = qt * 64 + w * 16 + lr;
#pragma unroll
    for (int rtile = 0; rtile < 2; ++rtile) {
        f32x4 a = rtile ? acc1 : acc0;
#pragma unroll
        for (int r = 0; r < 4; ++r) {
            int grow = rowbase + rtile * 16 + lk * 4 + r;
            float v = a[r];
            if (isP) {
                int n = grow - 1024;
                if (n < Nk + Ck + 1) P[(size_t)n * 1024 + q] = v;
            } else {
                QM[(size_t)(grow - 2048) * 1024 + q] = v;
            }
        }
    }
}

// ========== GRAM: per-class 34x34 gram (128 tasks) + qny (64 tasks) (grid 192) ==========
__global__ __launch_bounds__(256) void k_gram(float* Wbuf) {
    __shared__ __align__(16) float smA[34 * 68];
    WS_DECL
    const int t = threadIdx.x;
    const int lane = t & 63, wv = t >> 6;
    const int tau = blockIdx.x;
    if (tau < 128) {
        int c = tau >> 2, kc = tau & 3;
        float accg[5];
        int iu[5], ju[5];
#pragma unroll
        for (int u = 0; u < 5; ++u) {
            int e = t + u * 256;
            iu[u] = e / 34; ju[u] = e - iu[u] * 34;
            accg[u] = 0.f;
        }
        for (int kt = kc * 4; kt < kc * 4 + 4; ++kt) {
            for (int e2 = t; e2 < 34 * NB; e2 += 256) {
                int i = e2 >> 6, k = e2 & 63;
                int yr = (i < 32) ? (Qk + c * 32 + i) : ((i == 32) ? (Qk + Nk + c) : (Qk + Nk + Ck));
                size_t o = (size_t)yr * 1024 + kt * NB + k;
                smA[i * 68 + k] = bf2f(sOh[o]) + bf2f(sOm[o]) + bf2f(sOl[o]);
            }
            __syncthreads();
#pragma unroll
            for (int u = 0; u < 5; ++u) {
                int e = t + u * 256;
                if (e < 1156) {
                    float s = 0.f;
                    for (int k = 0; k < NB; ++k) s += smA[iu[u] * 68 + k] * smA[ju[u] * 68 + k];
                    accg[u] += s;
                }
            }
            __syncthreads();
        }
#pragma unroll
        for (int u = 0; u < 5; ++u) {
            int e = t + u * 256;
            if (e < 1156)
                atomicAdd(&Mbuf[c * 1224 + iu[u] * 36 + ju[u]], accg[u]);
        }
    } else {
        int rbase = (tau - 128) * 16;
        for (int j = wv; j < 16; j += 4) {
            size_t ro = (size_t)(rbase + j) * 1024;
            float s = 0.f;
            for (int d = lane; d < Dk; d += 64) {
                size_t o = ro + d;
                float v = bf2f(sOh[o]) + bf2f(sOm[o]) + bf2f(sOl[o]);
                s += v * v;
            }
            s = wave_red(s);
            if (lane == 0) qny[rbase + j] = s;
        }
    }
}

// ========== P5: 34x34 LDL + inverse + bias per class (grid 32) ==========
__global__ __launch_bounds__(256) void k_p5(float* Wbuf) {
    __shared__ float smem[2464];
    float* Ml = smem;          // stride 35
    float* Z  = smem + 1200;   // stride 35
    float* Dv = smem + 2400;
    WS_DECL
    const int t = threadIdx.x;
    const int c = blockIdx.x;
    float kN = cons[CO_KN + c], kap = cons[CO_KAPPA];
    for (int e = t; e < 34 * 34; e += 256) {
        int i = e / 34, j = e - i * 34;
        Ml[i * 35 + j] = Mbuf[c * 1224 + i * 36 + j];
    }
    __syncthreads();
    if (t == 0) {
        gmm[c] = Ml[32 * 35 + 32];
        Ml[32 * 35 + 32] += -1.f / kN;
        Ml[33 * 35 + 33] += 1.f / kap;
    }
    if (t < 32) Ml[t * 35 + t] += 1.f;
    __syncthreads();
    for (int j = 0; j < 34; ++j) {
        if (t == 0) {
            float s = Ml[j * 35 + j];
            for (int k = 0; k < j; ++k) s -= Ml[j * 35 + k] * Ml[j * 35 + k] * Dv[k];
            Dv[j] = s;
        }
        __syncthreads();
        if (t > j && t < 34) {
            float s = Ml[t * 35 + j];
            for (int k = 0; k < j; ++k) s -= Ml[t * 35 + k] * Ml[j * 35 + k] * Dv[k];
            Ml[t * 35 + j] = s / Dv[j];
        }
        __syncthreads();
    }
    if (t < 34) {
        for (int i = 0; i < 34; ++i) {
            float s = (i == t) ? 1.f : 0.f;
            for (int k = 0; k < i; ++k) s -= Ml[i * 35 + k] * Z[k * 35 + t];
            Z[i * 35 + t] = s;
        }
        for (int i = 33; i >= 0; --i) {
            float s = Z[i * 35 + t] / Dv[i];
            for (int k = i + 1; k < 34; ++k) s -= Ml[k * 35 + i] * Z[k * 35 + t];
            Z[i * 35 + t] = s;
        }
    }
    __syncthreads();
    for (int e = t; e < 34 * 34; e += 256) {
        int i = e / 34, j = e - i * 34;
        Minv[c * 1224 + i * 36 + j] = Z[i * 35 + j];
    }
    if (t == 0) {
        float ld = 0.f;
        for (int j = 0; j < 34; ++j) ld += logf(fabsf(Dv[j]));
        float scale = cons[CO_SCALE + c];
        float logdet = (float)Dk * logf(scale) + extraf[0] + logf(kN) + logf(kap) + ld;
        cons[CO_BIASF + c] = cons[CO_BIASA + c] - 0.5f * logdet;
    }
}

// ========== P6: epilogue, (qt, c) tasks (grid 512) ==========
__global__ __launch_bounds__(256) void k_p6(float* Wbuf, float* out) {
    __shared__ __align__(16) float smem[3904];
    float* Mi  = smem;          // stride 35 (1190)
    float* wL  = smem + 1200;   // stride 68 (2312)
    float* gsm = smem + 3520;   // 34
    float* red = smem + 3520 + 128;  // 256
    WS_DECL
    const int t = threadIdx.x;
    const int tau = blockIdx.x;
    int qt = tau >> 5, c = tau & 31;
    for (int e = t; e < 34 * 34; e += 256) {
        int i = e / 34, j = e - i * 34;
        Mi[i * 35 + j] = Minv[c * 1224 + i * 36 + j];
    }
    if (t < 34)
        gsm[t] = (t < 32) ? Mbuf[c * 1224 + t * 36 + 32]
                          : ((t == 32) ? gmm[c] : Mbuf[c * 1224 + 33 * 36 + 32]);
    __syncthreads();
    for (int e = t; e < 34 * NB; e += 256) {
        int i = e >> 6, qq = e & 63;
        int prow = (i < 32) ? (c * 32 + i) : ((i == 32) ? (Nk + c) : (Nk + Ck));
        wL[i * 68 + qq] = P[(size_t)prow * Qk + qt * NB + qq] - gsm[i];
    }
    __syncthreads();
    {
        int q = t & 63, part = t >> 6;
        int start = (part < 2) ? part * 9 : 18 + (part - 2) * 8;
        int cnt = (part < 2) ? 9 : 8;
        float partial = 0.f;
        for (int i = start; i < start + cnt; ++i) {
            float v = 0.f;
            for (int j = 0; j < 34; ++j) v += Mi[i * 35 + j] * wL[j * 68 + q];
            partial += v * wL[i * 68 + q];
        }
        red[part * 64 + q] = partial;
    }
    __syncthreads();
    if (t < 64) {
        int q = t;
        float quad = red[q] + red[64 + q] + red[128 + q] + red[192 + q];
        int qg = qt * NB + q;
        float w32 = wL[32 * 68 + q];
        float ydist2 = qny[qg] - 2.f * w32 - gmm[c];
        float dd = qno[qg] + mun2o[c] - 2.f * QM[(size_t)c * Qk + qg];
        float scale = cons[CO_SCALE + c], common = cons[CO_COMMON + c];
        float dist = (1.f - REGP) / scale * (ydist2 - quad) + REGP * dd;
        out[(size_t)qg * Ck + c] = cons[CO_BIASF + c] - cons[CO_COEF + c] * log1pf(dist / common);
    }
}

extern "C" void kernel_launch(void* const* d_in, const int* in_sizes, int n_in,
                              void* d_out, int out_size, void* d_ws, size_t ws_size,
                              hipStream_t stream) {
    const float* sx = (const float*)d_in[0];
    const float* qx = (const float*)d_in[1];
    const int* labels = (const int*)d_in[2];
    const float* mvec = (const float*)d_in[3];
    const float* kappa = (const float*)d_in[4];
    const float* nu = (const float*)d_in[5];
    const float* td = (const float*)d_in[6];
    const float* tl = (const float*)d_in[7];
    float* W = (float*)d_ws;
    float* out = (float*)d_out;

    hipLaunchKernelGGL(k_p0, dim3(152), dim3(256), 0, stream,
                       qx, labels, mvec, kappa, nu, td, tl, W);
    hipLaunchKernelGGL(k_p1, dim3(192), dim3(256), 0, stream, sx, mvec, W);
    hipLaunchKernelGGL(k_t1, dim3(8), dim3(256), 0, stream, tl, W);
    for (int l = 2; l <= 4; ++l) {
        int h = 32 << l, ht = h >> 6, pairs = 16 >> l;
        int nt = pairs * ht * ht;
        hipLaunchKernelGGL(k_tr_a, dim3(nt), dim3(256), 0, stream, tl, W, h, ht);
        hipLaunchKernelGGL(k_tr_b, dim3(nt), dim3(256), 0, stream, W, h, ht);
    }
    hipLaunchKernelGGL(k_cvt, dim3(784), dim3(256), 0, stream, W);
    hipLaunchKernelGGL(k_yg, dim3(1056), dim3(256), 0, stream, W);
    hipLaunchKernelGGL(k_p4m, dim3(560), dim3(256), 0, stream, W);
    hipLaunchKernelGGL(k_gram, dim3(192), dim3(256), 0, stream, W);
    hipLaunchKernelGGL(k_p5, dim3(32), dim3(256), 0, stream, W);
    hipLaunchKernelGGL(k_p6, dim3(512), dim3(256), 0, stream, W, out);
}

// Round 3
// 407.082 us; speedup vs baseline: 1.4145x; 1.4145x over previous
//
#include <hip/hip_runtime.h>
#include <math.h>

#define Dk 1024
#define Ck 32
#define Nk 1024
#define Qk 1024
#define REGP 0.5f
#define NB 64
#define NROWSV (Qk + Nk + Ck + 1)   // 2081 rows: queries, sorted support, mus, m

// consts layout (floats)
#define CO_KAPPA 0
#define CO_NU    1
#define CO_NJ    2
#define CO_KN    34
#define CO_SCALE 66
#define CO_COMMON 98
#define CO_COEF  130
#define CO_BIASA 162
#define CO_BIASF 200

// workspace offsets (floats). P aliases Y (Y dead after k_cvt, P born in k_p4m).
#define O_Y    0u
#define O_P    0u
#define O_W    2162688u
#define O_T    3211264u
#define O_MU   3473408u
#define O_QM   3506176u
#define O_MB   3538944u
#define O_MI   3578112u
#define O_QNY  3617280u
#define O_QNO  3618304u
#define O_MUN  3619328u
#define O_GMM  3619360u
#define O_EX   3619392u
#define O_CONS 3619408u
#define O_CIDX 3619664u
// bf16 split matrices (ushort storage, offsets in floats)
#define O_YH   3652432u
#define O_YM   4733776u
#define O_YL   5815120u
#define O_WH   6896464u
#define O_WM   7420752u
#define O_WL   7945040u
#define O_OH   8469328u
#define O_OM   9550672u
#define O_OL   10632016u
// total = 11,713,360 floats = 46.9 MB

#define WS_DECL \
    float* Y     = Wbuf + O_Y;    (void)Y; \
    float* P     = Wbuf + O_P;    (void)P; \
    float* W     = Wbuf + O_W;    (void)W; \
    float* Tb    = Wbuf + O_T;    (void)Tb; \
    float* mu    = Wbuf + O_MU;   (void)mu; \
    float* QM    = Wbuf + O_QM;   (void)QM; \
    float* Mbuf  = Wbuf + O_MB;   (void)Mbuf; \
    float* Minv  = Wbuf + O_MI;   (void)Minv; \
    float* qny   = Wbuf + O_QNY;  (void)qny; \
    float* qno   = Wbuf + O_QNO;  (void)qno; \
    float* mun2o = Wbuf + O_MUN;  (void)mun2o; \
    float* gmm   = Wbuf + O_GMM;  (void)gmm; \
    float* extraf= Wbuf + O_EX;   (void)extraf; \
    float* cons  = Wbuf + O_CONS; (void)cons; \
    int*   cidx  = (int*)(Wbuf + O_CIDX); (void)cidx; \
    ushort* sYh = (ushort*)(Wbuf + O_YH); (void)sYh; \
    ushort* sYm = (ushort*)(Wbuf + O_YM); (void)sYm; \
    ushort* sYl = (ushort*)(Wbuf + O_YL); (void)sYl; \
    ushort* sWh = (ushort*)(Wbuf + O_WH); (void)sWh; \
    ushort* sWm = (ushort*)(Wbuf + O_WM); (void)sWm; \
    ushort* sWl = (ushort*)(Wbuf + O_WL); (void)sWl; \
    ushort* sOh = (ushort*)(Wbuf + O_OH); (void)sOh; \
    ushort* sOm = (ushort*)(Wbuf + O_OM); (void)sOm; \
    ushort* sOl = (ushort*)(Wbuf + O_OL); (void)sOl;

typedef __attribute__((ext_vector_type(8))) __bf16 bf16x8;
typedef __attribute__((ext_vector_type(4))) float f32x4;

#define MFMA(a, b, c) __builtin_amdgcn_mfma_f32_16x16x32_bf16(a, b, c, 0, 0, 0)

__device__ __forceinline__ ushort f2bf(float x) {
    unsigned u = __float_as_uint(x);
    return (ushort)((u + 0x7FFFu + ((u >> 16) & 1u)) >> 16);
}
__device__ __forceinline__ float bf2f(ushort h) {
    return __uint_as_float(((unsigned)h) << 16);
}

__device__ __forceinline__ float wave_red(float s) {
#pragma unroll
    for (int o = 32; o > 0; o >>= 1) s += __shfl_down(s, o, 64);
    return s;
}

// ---------- LDS-staged bf16x3 MFMA tile machinery ----------
// LDS (halfword offsets): A comps [3][128][40], B comps [3][64][40]; 80B row stride
// → bank group (row*20)%32, max 2-way aliasing (free).
#define LDSA(c, r, k8) ((c) * 5120 + (r) * 40 + (k8))
#define LDSB(c, r, k8) (15360 + (c) * 2560 + (r) * 40 + (k8))
#define LDS_HW 23040   // 46080 bytes → 3 blocks/CU

__device__ __forceinline__ void tile_fetch(
    bf16x8* ra, bf16x8* rb,
    const ushort* Ah, const ushort* Am, const ushort* Al, int aRow0, int aRowMax,
    const ushort* Bh, const ushort* Bm, const ushort* Bl, int bRow0,
    int kcol, int t)
{
    bf16x8 z = {};
#pragma unroll
    for (int u = 0; u < 6; ++u) {
        const ushort* As = (u < 2) ? Ah : ((u < 4) ? Am : Al);
        int rem = ((u & 1) << 8) + t;
        int row = rem >> 2, kg = rem & 3;
        int gr = aRow0 + row;
        ra[u] = (gr < aRowMax) ? *(const bf16x8*)(As + (size_t)gr * 1024 + kcol + kg * 8) : z;
    }
#pragma unroll
    for (int u = 0; u < 3; ++u) {
        const ushort* Bs = (u == 0) ? Bh : ((u == 1) ? Bm : Bl);
        int row = t >> 2, kg = t & 3;
        rb[u] = *(const bf16x8*)(Bs + (size_t)(bRow0 + row) * 1024 + kcol + kg * 8);
    }
}

__device__ __forceinline__ void tile_store(ushort* lds, const bf16x8* ra, const bf16x8* rb, int t) {
#pragma unroll
    for (int u = 0; u < 6; ++u) {
        int rem = ((u & 1) << 8) + t;
        int row = rem >> 2, kg = rem & 3;
        *(bf16x8*)(lds + LDSA(u >> 1, row, kg * 8)) = ra[u];
    }
#pragma unroll
    for (int u = 0; u < 3; ++u) {
        int row = t >> 2, kg = t & 3;
        *(bf16x8*)(lds + LDSB(u, row, kg * 8)) = rb[u];
    }
}

// wave w computes 32 rows (w*32..) x 64 cols; 2x4 fragments of 16x16; 6-term bf16x3.
__device__ __forceinline__ void tile_compute(const ushort* lds, f32x4 acc[2][4],
                                             int w, int lr, int lk) {
    bf16x8 af[2][3], bf_[4][3];
#pragma unroll
    for (int rf = 0; rf < 2; ++rf)
#pragma unroll
        for (int c = 0; c < 3; ++c)
            af[rf][c] = *(const bf16x8*)(lds + LDSA(c, w * 32 + rf * 16 + lr, lk * 8));
#pragma unroll
    for (int cf = 0; cf < 4; ++cf)
#pragma unroll
        for (int c = 0; c < 3; ++c)
            bf_[cf][c] = *(const bf16x8*)(lds + LDSB(c, cf * 16 + lr, lk * 8));
#pragma unroll
    for (int rf = 0; rf < 2; ++rf)
#pragma unroll
        for (int cf = 0; cf < 4; ++cf) {
            f32x4 a = acc[rf][cf];
            a = MFMA(af[rf][0], bf_[cf][0], a);
            a = MFMA(af[rf][0], bf_[cf][1], a);
            a = MFMA(af[rf][1], bf_[cf][0], a);
            a = MFMA(af[rf][0], bf_[cf][2], a);
            a = MFMA(af[rf][2], bf_[cf][0], a);
            a = MFMA(af[rf][1], bf_[cf][1], a);
            acc[rf][cf] = a;
        }
}

__device__ __forceinline__ void tile_gemm(
    ushort* lds, f32x4 acc[2][4],
    const ushort* Ah, const ushort* Am, const ushort* Al, int aRow0, int aRowMax,
    const ushort* Bh, const ushort* Bm, const ushort* Bl, int bRow0,
    int ksteps, int t)
{
    const int w = t >> 6, lr = t & 15, lk = (t >> 4) & 3;
    bf16x8 ra[6], rb[3];
    tile_fetch(ra, rb, Ah, Am, Al, aRow0, aRowMax, Bh, Bm, Bl, bRow0, 0, t);
    tile_store(lds, ra, rb, t);
    __syncthreads();
    for (int kt = 0; kt < ksteps; ++kt) {
        if (kt + 1 < ksteps)
            tile_fetch(ra, rb, Ah, Am, Al, aRow0, aRowMax, Bh, Bm, Bl, bRow0, (kt + 1) * 32, t);
        tile_compute(lds, acc, w, lr, lk);
        __syncthreads();
        if (kt + 1 < ksteps)
            tile_store(lds, ra, rb, t);
        __syncthreads();
    }
}

// ---------- fp32 tile-GEMM machinery (trtri chain) ----------
__device__ __forceinline__ void fetch4(float4* reg, const float* src, int ld,
                                       int rowbase, int rowmax, int colbase, int t) {
#pragma unroll
    for (int u = 0; u < 4; ++u) {
        int slot = t + u * 256;
        int r = slot >> 4, c4 = slot & 15;
        int gr = rowbase + r;
        reg[u] = (gr < rowmax) ? *(const float4*)(src + (size_t)gr * ld + colbase + c4 * 4)
                               : make_float4(0.f, 0.f, 0.f, 0.f);
    }
}
__device__ __forceinline__ void stT(float* dst, const float4* reg, int t) {
#pragma unroll
    for (int u = 0; u < 4; ++u) {
        int slot = t + u * 256;
        int r = slot >> 4, c4 = slot & 15;
        dst[(c4 * 4 + 0) * 68 + r] = reg[u].x;
        dst[(c4 * 4 + 1) * 68 + r] = reg[u].y;
        dst[(c4 * 4 + 2) * 68 + r] = reg[u].z;
        dst[(c4 * 4 + 3) * 68 + r] = reg[u].w;
    }
}
__device__ __forceinline__ void stN(float* dst, const float4* reg, int t) {
#pragma unroll
    for (int u = 0; u < 4; ++u) {
        int slot = t + u * 256;
        int r = slot >> 4, c4 = slot & 15;
        *(float4*)(dst + r * 68 + c4 * 4) = reg[u];
    }
}
__device__ __forceinline__ void gemm16(const float* At, const float* Bt,
                                       float acc[4][4], int tx, int ty) {
#pragma unroll 4
    for (int kk = 0; kk < NB; ++kk) {
        float4 a = *(const float4*)(At + kk * 68 + ty * 4);
        float4 b = *(const float4*)(Bt + kk * 68 + tx * 4);
        float av[4] = {a.x, a.y, a.z, a.w};
        float bv[4] = {b.x, b.y, b.z, b.w};
#pragma unroll
        for (int r = 0; r < 4; ++r)
#pragma unroll
            for (int s = 0; s < 4; ++s) acc[r][s] += av[r] * bv[s];
    }
}
__device__ __forceinline__ void mm_task(
    const float* aSrc, int aLd, int aRow, int aRowMax, int aCol, int aRowStep, int aColStep,
    const float* bSrc, int bLd, int bRow, int bRowMax, int bCol, int bRowStep, int bColStep,
    bool bTrans, int k0, int k1,
    float acc[4][4], float* smA, float* smB, int t, int tx, int ty)
{
    float4 ra[4], rb[4];
    fetch4(ra, aSrc, aLd, aRow + k0 * aRowStep, aRowMax, aCol + k0 * aColStep, t);
    fetch4(rb, bSrc, bLd, bRow + k0 * bRowStep, bRowMax, bCol + k0 * bColStep, t);
    stT(smA, ra, t);
    if (bTrans) stT(smB, rb, t); else stN(smB, rb, t);
    __syncthreads();
    for (int kt = k0; kt < k1; ++kt) {
        if (kt + 1 < k1) {
            fetch4(ra, aSrc, aLd, aRow + (kt + 1) * aRowStep, aRowMax, aCol + (kt + 1) * aColStep, t);
            fetch4(rb, bSrc, bLd, bRow + (kt + 1) * bRowStep, bRowMax, bCol + (kt + 1) * bColStep, t);
        }
        gemm16(smA, smB, acc, tx, ty);
        __syncthreads();
        if (kt + 1 < k1) {
            stT(smA, ra, t);
            if (bTrans) stT(smB, rb, t); else stN(smB, rb, t);
        }
        __syncthreads();
    }
}

// ========== P0: stats, logdet, diag trtri, zero accum bufs, qno, copies (grid 152) ==========
__global__ __launch_bounds__(256) void k_p0(const float* qx, const int* labels,
                                            const float* mvec, const float* kappa,
                                            const float* nu, const float* td,
                                            const float* tl, float* Wbuf) {
    __shared__ __align__(16) float smem[9216];
    float* smA = smem;
    float* smB = smem + 4352;
    float* sX  = smem + 8704;
    WS_DECL
    const int t = threadIdx.x;
    const int lane = t & 63, wv = t >> 6;
    const int tau = blockIdx.x;

    if (tau == 0) {
        int* scnt = (int*)sX;
        if (t < Ck) scnt[t] = 0;
        __syncthreads();
        for (int n = t; n < Nk; n += 256) {
            int l = labels[n];
            int pos = atomicAdd(&scnt[l], 1);
            cidx[l * Nk + pos] = n;
        }
        __syncthreads();
        if (t < Ck) {
            float kap = fabsf(kappa[0]) + 1e-6f;
            float nu_ = fmaxf(nu[0], (float)(Dk - 1) + 1e-6f);
            float Njf = (float)scnt[t];
            float kN = kap + Njf;
            if (t == 0) { cons[CO_KAPPA] = kap; cons[CO_NU] = nu_; }
            cons[CO_NJ + t] = Njf;
            cons[CO_KN + t] = kN;
            cons[CO_SCALE + t] = (kN + 1.0f) / ((nu_ + Njf - (float)Dk + 1.0f) * kN);
            float common = nu_ + Njf + 1.0f - (float)Dk;
            cons[CO_COMMON + t] = common;
            cons[CO_COEF + t] = 0.5f * (common + (float)Dk);
            cons[CO_BIASA + t] = lgammaf(0.5f * (common + (float)Dk)) - lgammaf(0.5f * common)
                                 - 0.5f * (float)Dk * logf(common);
        }
    } else if (tau == 1) {
        float s = 0.f;
        for (int i = t; i < Dk; i += 256) s += logf(fabsf(td[i]));
        s = wave_red(s);
        if (lane == 0) sX[wv] = s;
        __syncthreads();
        if (t == 0) extraf[0] = 2.f * (sX[0] + sX[1] + sX[2] + sX[3]);
    } else if (tau < 18) {
        int I = tau - 2, b0 = I * NB;
        for (int idx = t; idx < NB * NB; idx += 256) {
            int r = idx >> 6, c = idx & 63;
            float v;
            if (c < r) v = tl[(size_t)(b0 + r) * Dk + b0 + c];
            else if (c == r) v = fabsf(td[b0 + r]);
            else v = 0.f;
            smA[r * 68 + c] = v;
        }
        __syncthreads();
        if (t < NB) {
            int j = t;
            smB[j * 68 + j] = 1.f / smA[j * 68 + j];
            for (int i = j + 1; i < NB; ++i) {
                float s = 0.f;
                for (int k = j; k < i; ++k) s += smA[i * 68 + k] * smB[k * 68 + j];
                smB[i * 68 + j] = -s / smA[i * 68 + i];
            }
        }
        __syncthreads();
        for (int idx = t; idx < NB * NB; idx += 256) {
            int r = idx >> 6, c = idx & 63;
            W[(size_t)(b0 + r) * Dk + b0 + c] = (c <= r) ? smB[r * 68 + c] : 0.f;
        }
    } else if (tau < 21) {         // zero Mbuf (32*1224 = 39168)
        int base = (tau - 18) * 13056;
        for (int i = t; i < 13056 && base + i < 39168; i += 256) Mbuf[base + i] = 0.f;
    } else if (tau == 21) {        // zero mun2o, gmm
        if (t < 32) { mun2o[t] = 0.f; gmm[t] = 0.f; }
    } else if (tau < 86) {         // qno (16 rows/task)
        int rbase = (tau - 22) * 16;
        for (int j = wv; j < 16; j += 4) {
            const float* row = qx + (size_t)(rbase + j) * Dk;
            float s = 0.f;
            for (int d = lane; d < Dk; d += 64) { float v = row[d]; s += v * v; }
            s = wave_red(s);
            if (lane == 0) qno[rbase + j] = s;
        }
    } else if (tau < 150) {        // copy queries into Y
        int rbase = (tau - 86) * 16;
        for (int j = 0; j < 16; ++j) {
            int r = rbase + j;
            ((float4*)(Y + (size_t)r * Dk))[t] = ((const float4*)(qx + (size_t)r * Dk))[t];
        }
    } else if (tau == 150) {       // m row
        ((float4*)(Y + (size_t)(Qk + Nk + Ck) * Dk))[t] = ((const float4*)mvec)[t];
    } else {                       // zero Y tail rows 2081..2111
        float4* z = (float4*)(Y + (size_t)2081 * Dk);
        for (int i = t; i < 31 * 256; i += 256) z[i] = make_float4(0, 0, 0, 0);
    }
}

// ========== P1: mu (+Y mu-row +mun2o), sorted-support copy (grid 192) ==========
__global__ __launch_bounds__(256) void k_p1(const float* sx, const float* mvec, float* Wbuf) {
    __shared__ float sX[512];
    WS_DECL
    const int t = threadIdx.x;
    const int lane = t & 63, wv = t >> 6;
    const int tau = blockIdx.x;
    if (tau < 128) {
        int c = tau >> 2;
        int d = ((tau & 3) << 8) + t;
        int Nj = (int)cons[CO_NJ + c];
        float kap = cons[CO_KAPPA], kN = cons[CO_KN + c];
        float acc = 0.f;
        for (int s = 0; s < Nj; ++s) acc += sx[(size_t)cidx[c * Nk + s] * Dk + d];
        float muv = (kap * mvec[d] + acc) / kN;
        mu[c * Dk + d] = muv;
        Y[(size_t)(Qk + Nk + c) * Dk + d] = muv;
        float s2 = wave_red(muv * muv);
        if (lane == 0) sX[wv] = s2;
        __syncthreads();
        if (t == 0) atomicAdd(&mun2o[c], sX[0] + sX[1] + sX[2] + sX[3]);
    } else {
        int rbase = (tau - 128) * 16;
        for (int j = 0; j < 16; ++j) {
            int n = rbase + j;
            int srcrow = cidx[(n >> 5) * Nk + (n & 31)];
            ((float4*)(Y + (size_t)(Qk + n) * Dk))[t] = ((const float4*)(sx + (size_t)srcrow * Dk))[t];
        }
    }
}

// ========== T1: trtri level-1 (merged A+B, local) (grid 8) ==========
__global__ __launch_bounds__(256) void k_t1(const float* tl, float* Wbuf) {
    __shared__ __align__(16) float smem[8704];
    float* smA = smem;
    float* smB = smem + 4352;
    WS_DECL
    const int t = threadIdx.x;
    const int tx = t & 15, ty = t >> 4;
    const int BIG = 1 << 30;
    int pb = blockIdx.x * 128;
    float acc[4][4] = {};
    mm_task(tl, Dk, pb + 64, BIG, pb, 0, NB,
            W, Dk, pb, BIG, pb, NB, 0, false, 0, 1,
            acc, smA, smB, t, tx, ty);
    {
        float4 ra[4];
        fetch4(ra, W, Dk, pb + 64, BIG, pb + 64, t);
#pragma unroll
        for (int r = 0; r < 4; ++r)
#pragma unroll
            for (int s = 0; s < 4; ++s)
                smB[(ty * 4 + r) * 68 + tx * 4 + s] = acc[r][s];
        stT(smA, ra, t);
    }
    __syncthreads();
    float acc2[4][4] = {};
    gemm16(smA, smB, acc2, tx, ty);
    __syncthreads();
#pragma unroll
    for (int r = 0; r < 4; ++r)
#pragma unroll
        for (int s = 0; s < 4; ++s)
            W[(size_t)(pb + 64 + ty * 4 + r) * Dk + pb + tx * 4 + s] = -acc2[r][s];
}

// ========== trtri level l phase A: T = B * Ainv ==========
__global__ __launch_bounds__(256) void k_tr_a(const float* tl, float* Wbuf, int h, int ht) {
    __shared__ __align__(16) float smem[8704];
    float* smA = smem;
    float* smB = smem + 4352;
    WS_DECL
    const int t = threadIdx.x;
    const int tx = t & 15, ty = t >> 4;
    const int BIG = 1 << 30;
    int tau = blockIdx.x;
    int p = tau / (ht * ht), rr = tau % (ht * ht);
    int i = rr / ht, j = rr % ht;
    int pb = p * 2 * h;
    float acc[4][4] = {};
    mm_task(tl, Dk, pb + h + i * NB, BIG, pb, 0, NB,
            W, Dk, pb, BIG, pb + j * NB, NB, 0, false, 0, ht,
            acc, smA, smB, t, tx, ty);
    float* Tp = Tb + (size_t)p * h * h;
#pragma unroll
    for (int r = 0; r < 4; ++r)
#pragma unroll
        for (int s = 0; s < 4; ++s)
            Tp[(size_t)(i * NB + ty * 4 + r) * h + j * NB + tx * 4 + s] = acc[r][s];
}

// ========== trtri level l phase B: W_off = -Cinv * T ==========
__global__ __launch_bounds__(256) void k_tr_b(float* Wbuf, int h, int ht) {
    __shared__ __align__(16) float smem[8704];
    float* smA = smem;
    float* smB = smem + 4352;
    WS_DECL
    const int t = threadIdx.x;
    const int tx = t & 15, ty = t >> 4;
    const int BIG = 1 << 30;
    int tau = blockIdx.x;
    int p = tau / (ht * ht), rr = tau % (ht * ht);
    int i = rr / ht, j = rr % ht;
    int pb = p * 2 * h;
    const float* Tp = Tb + (size_t)p * h * h;
    float acc[4][4] = {};
    mm_task(W, Dk, pb + h + i * NB, BIG, pb + h, 0, NB,
            Tp, h, 0, BIG, j * NB, NB, 0, false, 0, ht,
            acc, smA, smB, t, tx, ty);
#pragma unroll
    for (int r = 0; r < 4; ++r)
#pragma unroll
        for (int s = 0; s < 4; ++s)
            W[(size_t)(pb + h + i * NB + ty * 4 + r) * Dk + pb + j * NB + tx * 4 + s] = -acc[r][s];
}

// ========== CVT: exact 3-way bf16 split of Y (2112x1024) and W (1024x1024) (grid 784) ==========
__global__ __launch_bounds__(256) void k_cvt(float* Wbuf) {
    WS_DECL
    const int t = threadIdx.x;
#pragma unroll
    for (int u = 0; u < 4; ++u) {
        unsigned g = blockIdx.x * 1024u + u * 256u + t;   // float4 index, 0..802815
        bool isY = g < 540672u;
        float4 v = isY ? ((const float4*)Y)[g] : ((const float4*)W)[g - 540672u];
        ushort* ph = isY ? sYh : sWh;
        ushort* pm = isY ? sYm : sWm;
        ushort* pl = isY ? sYl : sWl;
        size_t o = (size_t)(isY ? g : (g - 540672u)) * 4;
        float vv[4] = {v.x, v.y, v.z, v.w};
        ushort4 H, M, L;
        ushort* Hp = (ushort*)&H; ushort* Mp = (ushort*)&M; ushort* Lp = (ushort*)&L;
#pragma unroll
        for (int c = 0; c < 4; ++c) {
            float x = vv[c];
            ushort h = f2bf(x);
            float r1 = x - bf2f(h);
            ushort m_ = f2bf(r1);
            ushort lo = f2bf(r1 - bf2f(m_));
            Hp[c] = h; Mp[c] = m_; Lp[c] = lo;
        }
        *(ushort4*)(ph + o) = H;
        *(ushort4*)(pm + o) = M;
        *(ushort4*)(pl + o) = L;
    }
}

// ========== YG: Yo = Y * W^T, LDS-staged bf16x3 MFMA (grid 272) ==========
// e -> jt descending (load balance: triangular K = (jt+1)*64)
__global__ __launch_bounds__(256) void k_yg(float* Wbuf) {
    __shared__ __align__(16) ushort lds[LDS_HW];
    WS_DECL
    const int t = threadIdx.x;
    int e = blockIdx.x;
    int jt = 15 - e / 17;
    int rt = e % 17;
    f32x4 acc[2][4] = {};
    tile_gemm(lds, acc, sYh, sYm, sYl, rt * 128, 2112,
              sWh, sWm, sWl, jt * 64, (jt + 1) * 2, t);
    const int w = t >> 6, lr = t & 15, lk = (t >> 4) & 3;
#pragma unroll
    for (int rf = 0; rf < 2; ++rf)
#pragma unroll
        for (int cf = 0; cf < 4; ++cf)
#pragma unroll
            for (int r = 0; r < 4; ++r) {
                int grow = rt * 128 + w * 32 + rf * 16 + lk * 4 + r;
                if (grow < NROWSV) {
                    float v = acc[rf][cf][r];
                    size_t o = (size_t)grow * 1024 + jt * 64 + cf * 16 + lr;
                    ushort h = f2bf(v);
                    float r1 = v - bf2f(h);
                    ushort m_ = f2bf(r1);
                    ushort lo = f2bf(r1 - bf2f(m_));
                    sOh[o] = h; sOm[o] = m_; sOl[o] = lo;
                }
            }
}

// ========== P4M: P = Yo_s * Yo_q^T (144 blocks) + QM = mu * qx^T (16 blocks) (grid 160) ==========
__global__ __launch_bounds__(256) void k_p4m(float* Wbuf) {
    __shared__ __align__(16) ushort lds[LDS_HW];
    WS_DECL
    const int t = threadIdx.x;
    int e = blockIdx.x;
    f32x4 acc[2][4] = {};
    const int w = t >> 6, lr = t & 15, lk = (t >> 4) & 3;
    if (e < 144) {
        int mt = e / 16, qt = e % 16;
        tile_gemm(lds, acc, sOh, sOm, sOl, 1024 + mt * 128, 2081,
                  sOh, sOm, sOl, qt * 64, 32, t);
#pragma unroll
        for (int rf = 0; rf < 2; ++rf)
#pragma unroll
            for (int cf = 0; cf < 4; ++cf)
#pragma unroll
                for (int r = 0; r < 4; ++r) {
                    int n = mt * 128 + w * 32 + rf * 16 + lk * 4 + r;
                    if (n < Nk + Ck + 1)
                        P[(size_t)n * 1024 + qt * 64 + cf * 16 + lr] = acc[rf][cf][r];
                }
    } else {
        int qt = e - 144;
        tile_gemm(lds, acc, sYh, sYm, sYl, 2048, 2080,
                  sYh, sYm, sYl, qt * 64, 32, t);
#pragma unroll
        for (int rf = 0; rf < 2; ++rf)
#pragma unroll
            for (int cf = 0; cf < 4; ++cf)
#pragma unroll
                for (int r = 0; r < 4; ++r) {
                    int rq = w * 32 + rf * 16 + lk * 4 + r;
                    if (rq < 32)
                        QM[(size_t)rq * 1024 + qt * 64 + cf * 16 + lr] = acc[rf][cf][r];
                }
    }
}

// ========== GRAM: per-class 34x34 gram (128 tasks) + qny (64 tasks) (grid 192) ==========
__global__ __launch_bounds__(256) void k_gram(float* Wbuf) {
    __shared__ __align__(16) float smA[34 * 68];
    WS_DECL
    const int t = threadIdx.x;
    const int lane = t & 63, wv = t >> 6;
    const int tau = blockIdx.x;
    if (tau < 128) {
        int c = tau >> 2, kc = tau & 3;
        float accg[5];
        int iu[5], ju[5];
#pragma unroll
        for (int u = 0; u < 5; ++u) {
            int e = t + u * 256;
            iu[u] = e / 34; ju[u] = e - iu[u] * 34;
            accg[u] = 0.f;
        }
        for (int kt = kc * 4; kt < kc * 4 + 4; ++kt) {
            for (int e2 = t; e2 < 34 * NB; e2 += 256) {
                int i = e2 >> 6, k = e2 & 63;
                int yr = (i < 32) ? (Qk + c * 32 + i) : ((i == 32) ? (Qk + Nk + c) : (Qk + Nk + Ck));
                size_t o = (size_t)yr * 1024 + kt * NB + k;
                smA[i * 68 + k] = bf2f(sOh[o]) + bf2f(sOm[o]) + bf2f(sOl[o]);
            }
            __syncthreads();
#pragma unroll
            for (int u = 0; u < 5; ++u) {
                int e = t + u * 256;
                if (e < 1156) {
                    float s = 0.f;
                    for (int k = 0; k < NB; ++k) s += smA[iu[u] * 68 + k] * smA[ju[u] * 68 + k];
                    accg[u] += s;
                }
            }
            __syncthreads();
        }
#pragma unroll
        for (int u = 0; u < 5; ++u) {
            int e = t + u * 256;
            if (e < 1156)
                atomicAdd(&Mbuf[c * 1224 + iu[u] * 36 + ju[u]], accg[u]);
        }
    } else {
        int rbase = (tau - 128) * 16;
        for (int j = wv; j < 16; j += 4) {
            size_t ro = (size_t)(rbase + j) * 1024;
            float s = 0.f;
            for (int d = lane; d < Dk; d += 64) {
                size_t o = ro + d;
                float v = bf2f(sOh[o]) + bf2f(sOm[o]) + bf2f(sOl[o]);
                s += v * v;
            }
            s = wave_red(s);
            if (lane == 0) qny[rbase + j] = s;
        }
    }
}

// ========== P5: 34x34 LDL + inverse + bias per class (grid 32) ==========
__global__ __launch_bounds__(256) void k_p5(float* Wbuf) {
    __shared__ float smem[2464];
    float* Ml = smem;          // stride 35
    float* Z  = smem + 1200;   // stride 35
    float* Dv = smem + 2400;
    WS_DECL
    const int t = threadIdx.x;
    const int c = blockIdx.x;
    float kN = cons[CO_KN + c], kap = cons[CO_KAPPA];
    for (int e = t; e < 34 * 34; e += 256) {
        int i = e / 34, j = e - i * 34;
        Ml[i * 35 + j] = Mbuf[c * 1224 + i * 36 + j];
    }
    __syncthreads();
    if (t == 0) {
        gmm[c] = Ml[32 * 35 + 32];
        Ml[32 * 35 + 32] += -1.f / kN;
        Ml[33 * 35 + 33] += 1.f / kap;
    }
    if (t < 32) Ml[t * 35 + t] += 1.f;
    __syncthreads();
    for (int j = 0; j < 34; ++j) {
        if (t == 0) {
            float s = Ml[j * 35 + j];
            for (int k = 0; k < j; ++k) s -= Ml[j * 35 + k] * Ml[j * 35 + k] * Dv[k];
            Dv[j] = s;
        }
        __syncthreads();
        if (t > j && t < 34) {
            float s = Ml[t * 35 + j];
            for (int k = 0; k < j; ++k) s -= Ml[t * 35 + k] * Ml[j * 35 + k] * Dv[k];
            Ml[t * 35 + j] = s / Dv[j];
        }
        __syncthreads();
    }
    if (t < 34) {
        for (int i = 0; i < 34; ++i) {
            float s = (i == t) ? 1.f : 0.f;
            for (int k = 0; k < i; ++k) s -= Ml[i * 35 + k] * Z[k * 35 + t];
            Z[i * 35 + t] = s;
        }
        for (int i = 33; i >= 0; --i) {
            float s = Z[i * 35 + t] / Dv[i];
            for (int k = i + 1; k < 34; ++k) s -= Ml[k * 35 + i] * Z[k * 35 + t];
            Z[i * 35 + t] = s;
        }
    }
    __syncthreads();
    for (int e = t; e < 34 * 34; e += 256) {
        int i = e / 34, j = e - i * 34;
        Minv[c * 1224 + i * 36 + j] = Z[i * 35 + j];
    }
    if (t == 0) {
        float ld = 0.f;
        for (int j = 0; j < 34; ++j) ld += logf(fabsf(Dv[j]));
        float scale = cons[CO_SCALE + c];
        float logdet = (float)Dk * logf(scale) + extraf[0] + logf(kN) + logf(kap) + ld;
        cons[CO_BIASF + c] = cons[CO_BIASA + c] - 0.5f * logdet;
    }
}

// ========== P6: epilogue, (qt, c) tasks (grid 512) ==========
__global__ __launch_bounds__(256) void k_p6(float* Wbuf, float* out) {
    __shared__ __align__(16) float smem[3904];
    float* Mi  = smem;          // stride 35 (1190)
    float* wL  = smem + 1200;   // stride 68 (2312)
    float* gsm = smem + 3520;   // 34
    float* red = smem + 3520 + 128;  // 256
    WS_DECL
    const int t = threadIdx.x;
    const int tau = blockIdx.x;
    int qt = tau >> 5, c = tau & 31;
    for (int e = t; e < 34 * 34; e += 256) {
        int i = e / 34, j = e - i * 34;
        Mi[i * 35 + j] = Minv[c * 1224 + i * 36 + j];
    }
    if (t < 34)
        gsm[t] = (t < 32) ? Mbuf[c * 1224 + t * 36 + 32]
                          : ((t == 32) ? gmm[c] : Mbuf[c * 1224 + 33 * 36 + 32]);
    __syncthreads();
    for (int e = t; e < 34 * NB; e += 256) {
        int i = e >> 6, qq = e & 63;
        int prow = (i < 32) ? (c * 32 + i) : ((i == 32) ? (Nk + c) : (Nk + Ck));
        wL[i * 68 + qq] = P[(size_t)prow * Qk + qt * NB + qq] - gsm[i];
    }
    __syncthreads();
    {
        int q = t & 63, part = t >> 6;
        int start = (part < 2) ? part * 9 : 18 + (part - 2) * 8;
        int cnt = (part < 2) ? 9 : 8;
        float partial = 0.f;
        for (int i = start; i < start + cnt; ++i) {
            float v = 0.f;
            for (int j = 0; j < 34; ++j) v += Mi[i * 35 + j] * wL[j * 68 + q];
            partial += v * wL[i * 68 + q];
        }
        red[part * 64 + q] = partial;
    }
    __syncthreads();
    if (t < 64) {
        int q = t;
        float quad = red[q] + red[64 + q] + red[128 + q] + red[192 + q];
        int qg = qt * NB + q;
        float w32 = wL[32 * 68 + q];
        float ydist2 = qny[qg] - 2.f * w32 - gmm[c];
        float dd = qno[qg] + mun2o[c] - 2.f * QM[(size_t)c * Qk + qg];
        float scale = cons[CO_SCALE + c], common = cons[CO_COMMON + c];
        float dist = (1.f - REGP) / scale * (ydist2 - quad) + REGP * dd;
        out[(size_t)qg * Ck + c] = cons[CO_BIASF + c] - cons[CO_COEF + c] * log1pf(dist / common);
    }
}

extern "C" void kernel_launch(void* const* d_in, const int* in_sizes, int n_in,
                              void* d_out, int out_size, void* d_ws, size_t ws_size,
                              hipStream_t stream) {
    const float* sx = (const float*)d_in[0];
    const float* qx = (const float*)d_in[1];
    const int* labels = (const int*)d_in[2];
    const float* mvec = (const float*)d_in[3];
    const float* kappa = (const float*)d_in[4];
    const float* nu = (const float*)d_in[5];
    const float* td = (const float*)d_in[6];
    const float* tl = (const float*)d_in[7];
    float* W = (float*)d_ws;
    float* out = (float*)d_out;

    hipLaunchKernelGGL(k_p0, dim3(152), dim3(256), 0, stream,
                       qx, labels, mvec, kappa, nu, td, tl, W);
    hipLaunchKernelGGL(k_p1, dim3(192), dim3(256), 0, stream, sx, mvec, W);
    hipLaunchKernelGGL(k_t1, dim3(8), dim3(256), 0, stream, tl, W);
    for (int l = 2; l <= 4; ++l) {
        int h = 32 << l, ht = h >> 6, pairs = 16 >> l;
        int nt = pairs * ht * ht;
        hipLaunchKernelGGL(k_tr_a, dim3(nt), dim3(256), 0, stream, tl, W, h, ht);
        hipLaunchKernelGGL(k_tr_b, dim3(nt), dim3(256), 0, stream, W, h, ht);
    }
    hipLaunchKernelGGL(k_cvt, dim3(784), dim3(256), 0, stream, W);
    hipLaunchKernelGGL(k_yg, dim3(272), dim3(256), 0, stream, W);
    hipLaunchKernelGGL(k_p4m, dim3(160), dim3(256), 0, stream, W);
    hipLaunchKernelGGL(k_gram, dim3(192), dim3(256), 0, stream, W);
    hipLaunchKernelGGL(k_p5, dim3(32), dim3(256), 0, stream, W);
    hipLaunchKernelGGL(k_p6, dim3(512), dim3(256), 0, stream, W, out);
}